// Round 5
// baseline (272.479 us; speedup 1.0000x reference)
//
#include <hip/hip_runtime.h>

// MemoryBank contrastive loss, steady state.
// B=1024, D=128, C=50, K=4096, N = C*K = 204800. TEMP=0.3.
// loss = (1/B) * sum_b w_b * ( ln(sum exp(dot/T)) - dot_pos/T )
// SCALE = log2(e)/T folded into normalized bf16 features: MFMA acc feeds exp2.
//
// R9: occupancy, not traffic. Ladder evidence: R5(8 waves/CU)=87, R8(8)=88,
// R7(16)=78.6 -- duration tracks waves/CU, not LDS bytes (R8 halved LDS
// traffic vs R5 at zero conflicts and gained nothing). Kernel is latency-
// bound: per-CU pipe demand (LDS 16us, MFMA 6.5us, trans ~11us, HBM ~8us)
// is far below the 88us measured; ~70% is unhidden HBM/LDS latency with
// only 2 blocks/CU to overlap. R8's footprint is co-residency-optimal:
// VGPR 96 -> 5 waves/SIMD; LDS 32KB -> 5 blocks/CU = 160KB exactly. So:
// grid (320,4) = 1280 blocks = ALL simultaneously resident (5/CU x 256),
// 20 waves/CU (62.5%), NITER = 3200/320 = 10, no tail. y-partners at
// xc+320k: 320%8=0 -> same XCD -> L2 dedupe preserved. Hot loop source
// untouched vs R8 -> identical codegen (VGPR_Count 96 is the check).
// Keeps: mf=4 (64 rows/wave, LDS floor 16us/CU), fragment-linear bf16 LDS
// (0 conflicts, pack-once), T14 split (loads t+1 in flight across COMPUTE).

#define XCHUNK 320
#define NITER 10           // 320 * 10 = 3200 tiles of 64 rows = 204800
#define TILE_BYTES 32768   // 64 rows x 128 fp32
#define LN2f 0.6931471805599453f
#define SCALEf 4.808983469629878f   // log2(e)/0.3

typedef __attribute__((ext_vector_type(8))) short bf16x8;
typedef __attribute__((ext_vector_type(4))) float f32x4;
typedef unsigned int u32;

__device__ __forceinline__ unsigned short f2bf(float x) {
    union { float f; unsigned int u; } c; c.f = x;
    unsigned int u = c.u;
    u = (u + 0x7fffu + ((u >> 16) & 1u)) >> 16;   // RNE (features only)
    return (unsigned short)u;
}
__device__ __forceinline__ float bf2f(unsigned short h) {
    union { unsigned int u; float f; } c; c.u = ((unsigned int)h) << 16;
    return c.f;
}
// two fp32 -> two bf16 (truncation) in one v_perm_b32: [bf(lo) | bf(hi)<<16]
__device__ __forceinline__ unsigned int pack_bf2(float lo, float hi) {
    union { float f; unsigned int u; } a, b; a.f = lo; b.f = hi;
    return __builtin_amdgcn_perm(b.u, a.u, 0x07060302u);
}

// ---- Kernel 1: normalize+scale features -> bf16; zero S and out -------------
__global__ void normalize_feat(const float* __restrict__ f,
                               unsigned short* __restrict__ featb,
                               float* __restrict__ S,
                               float* __restrict__ out) {
    const int b = blockIdx.x;          // 1024 blocks
    const int t = threadIdx.x;         // 128 threads
    if (t == 0) S[b] = 0.0f;
    if (b == 0 && t == 1) *out = 0.0f;
    float v = f[b * 128 + t];
    float ss = v * v;
    #pragma unroll
    for (int m = 1; m < 64; m <<= 1) ss += __shfl_xor(ss, m, 64);
    __shared__ float wsum[2];
    if ((t & 63) == 0) wsum[t >> 6] = ss;
    __syncthreads();
    float tot = wsum[0] + wsum[1];
    float inv = SCALEf / fmaxf(sqrtf(tot), 1e-12f);
    featb[b * 128 + t] = f2bf(v * inv);
}

// ---- Kernel 2: fused GEMM + exp2-sum ----------------------------------------
// 256 thr = 4 waves; wave owns 64 m-rows (mf=4), n-tile 64, K=128 complete.
__global__ __launch_bounds__(256, 2) void gemm_lse(
        const unsigned short* __restrict__ featb,  // [1024][128] bf16 (scaled)
        const float* __restrict__ mem,             // [204800][128] fp32
        float* __restrict__ S)                     // [1024] exp2-sums
{
    // 2 x 16 KB bf16 tiles, fragment-linear: slot (nf*4+ks)*64 + lane, 16 B each
    __shared__ uint4 ldsb[2][1024];

    const int tid  = threadIdx.x;
    const int wave = tid >> 6;        // 0..3
    const int lane = tid & 63;
    const int col  = lane & 15;
    const int quad = lane >> 4;

    const int m_wave = blockIdx.y * 256 + wave * 64;
    const int xc = blockIdx.x;        // 0..319

    // A fragments: A[m=col][k=quad*8+j], mf=4 x ks=4 (64 VGPR, AGPR-eligible)
    bf16x8 afrag[4][4];
    #pragma unroll
    for (int mf = 0; mf < 4; ++mf)
        #pragma unroll
        for (int ks = 0; ks < 4; ++ks)
            afrag[mf][ks] = *(const bf16x8*)&featb[(size_t)(m_wave + mf * 16 + col) * 128
                                                   + ks * 32 + quad * 8];

    float s_part[16];
    #pragma unroll
    for (int i = 0; i < 16; ++i) s_part[i] = 0.0f;

    // Tile-invariant global byte offsets for this thread's four 32 B fp32
    // chunks. Thread t fills LDS slots {t, 256+t, 512+t, 768+t} (lane-linear
    // writes); the permutation lives on the GLOBAL side:
    // slot -> (nf,ks,quad,col) -> row (nf*16+col), k-bytes ks*128+quad*32.
    int o[4];
    #pragma unroll
    for (int j = 0; j < 4; ++j) {
        int Sl = j * 256 + tid;           // slot index 0..1023
        int Fi = Sl >> 6, L = Sl & 63;    // fragment id, lane within fragment
        int snf = Fi >> 2, sks = Fi & 3, sq = L >> 4, sc = L & 15;
        o[j] = (snf * 16 + sc) * 512 + sks * 128 + sq * 32;
    }

    // staged registers: 128 B fp32 in flight across COMPUTE (32 VGPR)
    float4 ga[4], gb[4];

    #define LOADS(t_) {                                                         \
        const char* gt = (const char*)mem + (size_t)(xc + XCHUNK * (t_)) * TILE_BYTES; \
        _Pragma("unroll")                                                       \
        for (int j = 0; j < 4; ++j) {                                           \
            ga[j] = *(const float4*)(gt + o[j]);                                \
            gb[j] = *(const float4*)(gt + o[j] + 16);                           \
        } }

    #define PACKWRITE(bi) {                                                     \
        _Pragma("unroll")                                                       \
        for (int j = 0; j < 4; ++j) {                                           \
            uint4 pk;                                                           \
            pk.x = pack_bf2(ga[j].x, ga[j].y); pk.y = pack_bf2(ga[j].z, ga[j].w); \
            pk.z = pack_bf2(gb[j].x, gb[j].y); pk.w = pack_bf2(gb[j].z, gb[j].w); \
            ldsb[bi][j * 256 + tid] = pk;                                       \
        } }

    #define COMPUTE(bi) {                                                       \
        _Pragma("unroll")                                                       \
        for (int nf = 0; nf < 4; ++nf) {                                        \
            f32x4 acc[4];                                                       \
            _Pragma("unroll")                                                   \
            for (int mf = 0; mf < 4; ++mf) acc[mf] = (f32x4)(0.0f);             \
            _Pragma("unroll")                                                   \
            for (int ks = 0; ks < 4; ++ks) {                                    \
                bf16x8 bfrag = *(const bf16x8*)&ldsb[bi][(nf * 4 + ks) * 64 + lane]; \
                _Pragma("unroll")                                               \
                for (int mf = 0; mf < 4; ++mf)                                  \
                    acc[mf] = __builtin_amdgcn_mfma_f32_16x16x32_bf16(          \
                        afrag[mf][ks], bfrag, acc[mf], 0, 0, 0);                \
            }                                                                   \
            _Pragma("unroll")                                                   \
            for (int mf = 0; mf < 4; ++mf)                                      \
                _Pragma("unroll")                                               \
                for (int r = 0; r < 4; ++r)                                     \
                    s_part[mf * 4 + r] += __builtin_amdgcn_exp2f(acc[mf][r]);   \
        } }

    // prologue: stage tile 0 into buf0
    LOADS(0)
    PACKWRITE(0)
    __syncthreads();

    for (int t = 0; t < NITER; ++t) {
        if (t + 1 < NITER) LOADS(t + 1)       // in flight during compute
        COMPUTE(t & 1)
        if (t + 1 < NITER) PACKWRITE((t + 1) & 1)  // other buffer; last read 2 barriers ago
        __syncthreads();
    }

    // reduce across the 16 col-lanes sharing the same quad
    #pragma unroll
    for (int d = 1; d < 16; d <<= 1)
        #pragma unroll
        for (int i = 0; i < 16; ++i)
            s_part[i] += __shfl_xor(s_part[i], d, 64);

    if (col == 0) {
        #pragma unroll
        for (int i = 0; i < 16; ++i) {
            int row = m_wave + (i >> 2) * 16 + quad * 4 + (i & 3);
            atomicAdd(&S[row], s_part[i]);
        }
    }
    #undef LOADS
    #undef PACKWRITE
    #undef COMPUTE
}

// ---- Kernel 3: pos logit + weighted mean ------------------------------------
__global__ void finalize_k(const unsigned short* __restrict__ featb,
                           const float* __restrict__ mem,
                           const int* __restrict__ labels,
                           const float* __restrict__ S,
                           float* __restrict__ out) {
    const int wave = threadIdx.x >> 6;
    const int lane = threadIdx.x & 63;
    const int b = blockIdx.x * 4 + wave;          // 256 blocks x 4 waves = 1024
    const int lab = labels[b];
    const float* mrow = mem + (size_t)lab * (4096 * 128);   // memory[lab][0][:]
    float fa = bf2f(featb[b * 128 + lane]);
    float fc = bf2f(featb[b * 128 + lane + 64]);
    float p = fa * mrow[lane] + fc * mrow[lane + 64];       // t_pos (log2 domain)
    #pragma unroll
    for (int m = 1; m < 64; m <<= 1) p += __shfl_xor(p, m, 64);
    if (lane == 0) {
        float w = (lab < 2) ? 1.3f : 1.0f;
        float v = w * LN2f * (log2f(S[b]) - p) * (1.0f / 1024.0f);
        atomicAdd(out, v);
    }
}

extern "C" void kernel_launch(void* const* d_in, const int* in_sizes, int n_in,
                              void* d_out, int out_size, void* d_ws, size_t ws_size,
                              hipStream_t stream) {
    const float* features = (const float*)d_in[0];
    const int*   labels   = (const int*)d_in[1];
    const float* memory   = (const float*)d_in[2];
    float* out = (float*)d_out;

    unsigned short* featb = (unsigned short*)d_ws;               // 256 KiB
    float* S = (float*)((char*)d_ws + 1024 * 128 * 2);           // 1024 floats

    normalize_feat<<<1024, 128, 0, stream>>>(features, featb, S, out);
    gemm_lse<<<dim3(XCHUNK, 4), 256, 0, stream>>>(featb, memory, S);
    finalize_k<<<256, 256, 0, stream>>>(featb, memory, labels, S, out);
}

// Round 6
// 238.610 us; speedup vs baseline: 1.1419x; 1.1419x over previous
//
#include <hip/hip_runtime.h>

// MemoryBank contrastive loss, steady state.
// B=1024, D=128, C=50, K=4096, N = C*K = 204800. TEMP=0.3.
// loss = (1/B) * sum_b w_b * ( ln(sum exp(dot/T)) - dot_pos/T )
// SCALE = log2(e)/T folded into normalized bf16 features: MFMA acc feeds exp2.
//
// R10: occupancy via the PROVEN kernel. Ladder: fixed 8 waves/CU, 4x LDS
// traffic cut changed nothing (R5 87.4 -> R8 88.0); 8->16 waves/CU gained
// 11% (R8 88 -> R7 78.6) -> latency-bound, occupancy is the lever. R9's
// 5/CU attempt used 160/160 KB LDS (zero slack) and regressed to 147 us
// (non-resident tail at 1 block/CU). R10 pushes occupancy SAFELY: R7's
// exact hot loop (mf=2, 512 thr, VGPR 52, 32 KB LDS) at 4 blocks/CU =
// 32 waves/CU = 100% thread occupancy. Grid (256,4) = 1024 blocks, ALL
// resident: threads 4x512=2048 (= measured cap), LDS 128/160 KB (slack),
// VGPR 8 waves/SIMD x 52 = 416 <= 512. 3200 tiles / 256 = 12.5: xc<128
// blocks run 13 tiles, rest 12 (runtime nt, guarded prefetch) -- ~4%
// imbalance, no tail. y-partners 256 apart: 256%8=0 -> same XCD, L2/L3
// dedupe preserved. If this lands ~70 us instead of ~55, LDS-BW (1.64 GB)
// became binding -> port mf=4 into this grid next.
// Keeps: fragment-linear bf16 LDS (0 conflicts, pack-once), T14 split.

#define XCHUNK 256
#define NTILES 3200        // 204800 rows / 64 rows per tile
#define TILE_BYTES 32768   // 64 rows x 128 fp32
#define LN2f 0.6931471805599453f
#define SCALEf 4.808983469629878f   // log2(e)/0.3

typedef __attribute__((ext_vector_type(8))) short bf16x8;
typedef __attribute__((ext_vector_type(4))) float f32x4;
typedef unsigned int u32;

__device__ __forceinline__ unsigned short f2bf(float x) {
    union { float f; unsigned int u; } c; c.f = x;
    unsigned int u = c.u;
    u = (u + 0x7fffu + ((u >> 16) & 1u)) >> 16;   // RNE (features only)
    return (unsigned short)u;
}
__device__ __forceinline__ float bf2f(unsigned short h) {
    union { unsigned int u; float f; } c; c.u = ((unsigned int)h) << 16;
    return c.f;
}
// two fp32 -> two bf16 (truncation) in one v_perm_b32: [bf(lo) | bf(hi)<<16]
__device__ __forceinline__ unsigned int pack_bf2(float lo, float hi) {
    union { float f; unsigned int u; } a, b; a.f = lo; b.f = hi;
    return __builtin_amdgcn_perm(b.u, a.u, 0x07060302u);
}

// ---- Kernel 1: normalize+scale features -> bf16; zero S and out -------------
__global__ void normalize_feat(const float* __restrict__ f,
                               unsigned short* __restrict__ featb,
                               float* __restrict__ S,
                               float* __restrict__ out) {
    const int b = blockIdx.x;          // 1024 blocks
    const int t = threadIdx.x;         // 128 threads
    if (t == 0) S[b] = 0.0f;
    if (b == 0 && t == 1) *out = 0.0f;
    float v = f[b * 128 + t];
    float ss = v * v;
    #pragma unroll
    for (int m = 1; m < 64; m <<= 1) ss += __shfl_xor(ss, m, 64);
    __shared__ float wsum[2];
    if ((t & 63) == 0) wsum[t >> 6] = ss;
    __syncthreads();
    float tot = wsum[0] + wsum[1];
    float inv = SCALEf / fmaxf(sqrtf(tot), 1e-12f);
    featb[b * 128 + t] = f2bf(v * inv);
}

// ---- Kernel 2: fused GEMM + exp2-sum ----------------------------------------
// 512 thr = 8 waves; wave owns 32 m-rows (mf=2), n-tile 64, K=128 complete.
__global__ __launch_bounds__(512, 4) void gemm_lse(
        const unsigned short* __restrict__ featb,  // [1024][128] bf16 (scaled)
        const float* __restrict__ mem,             // [204800][128] fp32
        float* __restrict__ S)                     // [1024] exp2-sums
{
    // 2 x 16 KB bf16 tiles, fragment-linear: slot (nf*4+ks)*64 + lane, 16 B each
    __shared__ uint4 ldsb[2][1024];

    const int tid  = threadIdx.x;
    const int wave = tid >> 6;        // 0..7
    const int lane = tid & 63;
    const int col  = lane & 15;
    const int quad = lane >> 4;

    const int m_wave = blockIdx.y * 256 + wave * 32;
    const int xc = blockIdx.x;        // 0..255
    // 3200 = 256*12 + 128: blocks xc<128 process 13 tiles, others 12
    const int nt = (xc < (NTILES - XCHUNK * 12)) ? 13 : 12;

    // A fragments: A[m=col][k=quad*8+j], mf=2 x ks=4 (32 VGPR)
    bf16x8 afrag[2][4];
    #pragma unroll
    for (int mf = 0; mf < 2; ++mf)
        #pragma unroll
        for (int ks = 0; ks < 4; ++ks)
            afrag[mf][ks] = *(const bf16x8*)&featb[(size_t)(m_wave + mf * 16 + col) * 128
                                                   + ks * 32 + quad * 8];

    float s_part[8];
    #pragma unroll
    for (int i = 0; i < 8; ++i) s_part[i] = 0.0f;

    // Tile-invariant global byte offsets for this thread's two 32 B fp32
    // chunks. Thread t fills LDS slots {t, 512+t} (lane-linear writes); the
    // permutation lives on the GLOBAL side: slot -> (nf,ks,quad,col) ->
    // row (nf*16+col), k-bytes ks*128+quad*32.
    int o[2];
    #pragma unroll
    for (int j = 0; j < 2; ++j) {
        int Sl = j * 512 + tid;           // slot index 0..1023
        int Fi = Sl >> 6, L = Sl & 63;    // fragment id, lane within fragment
        int snf = Fi >> 2, sks = Fi & 3, sq = L >> 4, sc = L & 15;
        o[j] = (snf * 16 + sc) * 512 + sks * 128 + sq * 32;
    }

    // staged registers: 64 B fp32 in flight across COMPUTE (16 VGPR)
    float4 g0a, g0b, g1a, g1b;

    #define LOADS(t_) {                                                         \
        const char* gt = (const char*)mem + (size_t)(xc + XCHUNK * (t_)) * TILE_BYTES; \
        g0a = *(const float4*)(gt + o[0]);                                      \
        g0b = *(const float4*)(gt + o[0] + 16);                                 \
        g1a = *(const float4*)(gt + o[1]);                                      \
        g1b = *(const float4*)(gt + o[1] + 16); }

    #define PACKWRITE(bi) {                                                     \
        uint4 pk;                                                               \
        pk.x = pack_bf2(g0a.x, g0a.y); pk.y = pack_bf2(g0a.z, g0a.w);           \
        pk.z = pack_bf2(g0b.x, g0b.y); pk.w = pack_bf2(g0b.z, g0b.w);           \
        ldsb[bi][tid] = pk;                                                     \
        pk.x = pack_bf2(g1a.x, g1a.y); pk.y = pack_bf2(g1a.z, g1a.w);           \
        pk.z = pack_bf2(g1b.x, g1b.y); pk.w = pack_bf2(g1b.z, g1b.w);           \
        ldsb[bi][512 + tid] = pk; }

    #define COMPUTE(bi) {                                                       \
        _Pragma("unroll")                                                       \
        for (int nf = 0; nf < 4; ++nf) {                                        \
            f32x4 acc[2];                                                       \
            _Pragma("unroll")                                                   \
            for (int mf = 0; mf < 2; ++mf) acc[mf] = (f32x4)(0.0f);             \
            _Pragma("unroll")                                                   \
            for (int ks = 0; ks < 4; ++ks) {                                    \
                bf16x8 bfrag = *(const bf16x8*)&ldsb[bi][(nf * 4 + ks) * 64 + lane]; \
                _Pragma("unroll")                                               \
                for (int mf = 0; mf < 2; ++mf)                                  \
                    acc[mf] = __builtin_amdgcn_mfma_f32_16x16x32_bf16(          \
                        afrag[mf][ks], bfrag, acc[mf], 0, 0, 0);                \
            }                                                                   \
            _Pragma("unroll")                                                   \
            for (int mf = 0; mf < 2; ++mf)                                      \
                _Pragma("unroll")                                               \
                for (int r = 0; r < 4; ++r)                                     \
                    s_part[mf * 4 + r] += __builtin_amdgcn_exp2f(acc[mf][r]);   \
        } }

    // prologue: stage tile 0 into buf0
    LOADS(0)
    PACKWRITE(0)
    __syncthreads();

    for (int t = 0; t < nt; ++t) {
        if (t + 1 < nt) LOADS(t + 1)          // in flight during compute
        COMPUTE(t & 1)
        if (t + 1 < nt) PACKWRITE((t + 1) & 1)     // other buffer; last read 2 barriers ago
        __syncthreads();
    }

    // reduce across the 16 col-lanes sharing the same quad
    #pragma unroll
    for (int d = 1; d < 16; d <<= 1)
        #pragma unroll
        for (int i = 0; i < 8; ++i)
            s_part[i] += __shfl_xor(s_part[i], d, 64);

    if (col == 0) {
        #pragma unroll
        for (int i = 0; i < 8; ++i) {
            int row = m_wave + (i >> 2) * 16 + quad * 4 + (i & 3);
            atomicAdd(&S[row], s_part[i]);
        }
    }
    #undef LOADS
    #undef PACKWRITE
    #undef COMPUTE
}

// ---- Kernel 3: pos logit + weighted mean ------------------------------------
__global__ void finalize_k(const unsigned short* __restrict__ featb,
                           const float* __restrict__ mem,
                           const int* __restrict__ labels,
                           const float* __restrict__ S,
                           float* __restrict__ out) {
    const int wave = threadIdx.x >> 6;
    const int lane = threadIdx.x & 63;
    const int b = blockIdx.x * 4 + wave;          // 256 blocks x 4 waves = 1024
    const int lab = labels[b];
    const float* mrow = mem + (size_t)lab * (4096 * 128);   // memory[lab][0][:]
    float fa = bf2f(featb[b * 128 + lane]);
    float fc = bf2f(featb[b * 128 + lane + 64]);
    float p = fa * mrow[lane] + fc * mrow[lane + 64];       // t_pos (log2 domain)
    #pragma unroll
    for (int m = 1; m < 64; m <<= 1) p += __shfl_xor(p, m, 64);
    if (lane == 0) {
        float w = (lab < 2) ? 1.3f : 1.0f;
        float v = w * LN2f * (log2f(S[b]) - p) * (1.0f / 1024.0f);
        atomicAdd(out, v);
    }
}

extern "C" void kernel_launch(void* const* d_in, const int* in_sizes, int n_in,
                              void* d_out, int out_size, void* d_ws, size_t ws_size,
                              hipStream_t stream) {
    const float* features = (const float*)d_in[0];
    const int*   labels   = (const int*)d_in[1];
    const float* memory   = (const float*)d_in[2];
    float* out = (float*)d_out;

    unsigned short* featb = (unsigned short*)d_ws;               // 256 KiB
    float* S = (float*)((char*)d_ws + 1024 * 128 * 2);           // 1024 floats

    normalize_feat<<<1024, 128, 0, stream>>>(features, featb, S, out);
    gemm_lse<<<dim3(XCHUNK, 4), 512, 0, stream>>>(featb, memory, S);
    finalize_k<<<256, 256, 0, stream>>>(featb, memory, labels, S, out);
}